// Round 8
// baseline (2027.239 us; speedup 1.0000x reference)
//
#include <hip/hip_runtime.h>
#include <hip/hip_bf16.h>
#include <stdint.h>
#include <math.h>

#define NUM_FF 7
#define DM 512
#define RD 128
#define VOCABN 128
#define BATCH 128
#define TLEN 1024

typedef unsigned int u32x4 __attribute__((ext_vector_type(4)));

// LDS word-offsets inside the dynamic segment
#define WOFF 0            // 16 chunks x 512 threads x 4 words = 32768 words (layers 0-3)
#define XQ0W 32768        // 16 words
#define XQ1W 32784        // 16 words
#define HXW  32800        // 4 words
#define EMBW 32816        // 512 words
#define TOKW 33328        // 1026 words
#define SMWORDS 34356     // round up
#define SMBYTES (SMWORDS * 4)

// ---- pack ff into per-thread-contiguous chunks:
// ffq[(l*4+q)*2048 + j*4 + k] bit i = (ff[l][32*(q*4+k)+i][j] > 0)
// so thread j's 16B chunk for (layer l, quarter q) is one dwordx4, and the
// global layout for chunks 0..15 matches the LDS staging layout verbatim. ----
__global__ void pack_ff_kernel(const float* __restrict__ ff, uint32_t* __restrict__ ffq) {
    int idx = blockIdx.x * blockDim.x + threadIdx.x;
    if (idx >= NUM_FF * 16 * DM) return;
    int j = idx & (DM - 1);
    int m = (idx >> 9) & 15;   // word index 0..15
    int l = idx >> 13;
    const float* base = ff + (size_t)l * DM * DM + (size_t)(m * 32) * DM + j;
    uint32_t w = 0;
#pragma unroll
    for (int i = 0; i < 32; ++i)
        w |= (base[(size_t)i * DM] > 0.0f ? 1u : 0u) << i;
    ffq[(l * 4 + (m >> 2)) * (DM * 4) + j * 4 + (m & 3)] = w;
}

// ---- integer thresholds: bit = (512-2a >= th)  <=>  a <= floor((512-th)/2) ----
__global__ void pack_thresh_kernel(const float* __restrict__ th, int* __restrict__ it) {
    int idx = blockIdx.x * blockDim.x + threadIdx.x;
    if (idx < NUM_FF * DM)
        it[idx] = (int)floor((512.0 - (double)th[idx]) * 0.5);
}

// ---- pack embed/head/initial (512 threads, 1 block) ----
__global__ void pack_small_kernel(const float* __restrict__ embed,
                                  const float* __restrict__ head,
                                  const float* __restrict__ initial,
                                  uint32_t* __restrict__ embp,
                                  uint32_t* __restrict__ headp,
                                  uint32_t* __restrict__ initp) {
    int idx = threadIdx.x; // 512
    {   // embp[v*4+k] bit i = embed[v][32k+i] > 0
        int v = idx >> 2, k = idx & 3;
        uint32_t w = 0;
#pragma unroll
        for (int i = 0; i < 32; ++i)
            w |= (embed[v * RD + k * 32 + i] > 0.0f ? 1u : 0u) << i;
        embp[idx] = w;
    }
    {   // headp[k*128+v] bit i = head[32k+i][v] > 0
        int k = idx >> 7, v = idx & 127;
        uint32_t w = 0;
#pragma unroll
        for (int i = 0; i < 32; ++i)
            w |= (head[(k * 32 + i) * VOCABN + v] > 0.0f ? 1u : 0u) << i;
        headp[idx] = w;
    }
    if (idx < 16) {
        uint32_t w = 0;
#pragma unroll
        for (int i = 0; i < 32; ++i)
            w |= (initial[idx * 32 + i] > 0.0f ? 1u : 0u) << i;
        initp[idx] = w;
    }
}

__device__ __forceinline__ int bdot4r(uint4 s0, uint4 s1, uint4 s2, uint4 s3,
                                      u32x4 w0, u32x4 w1, u32x4 w2, u32x4 w3) {
    int a = __popc(s0.x ^ w0[0]);
    a += __popc(s0.y ^ w0[1]);
    a += __popc(s0.z ^ w0[2]);
    a += __popc(s0.w ^ w0[3]);
    a += __popc(s1.x ^ w1[0]);
    a += __popc(s1.y ^ w1[1]);
    a += __popc(s1.z ^ w1[2]);
    a += __popc(s1.w ^ w1[3]);
    int c = __popc(s2.x ^ w2[0]);
    c += __popc(s2.y ^ w2[1]);
    c += __popc(s2.z ^ w2[2]);
    c += __popc(s2.w ^ w2[3]);
    c += __popc(s3.x ^ w3[0]);
    c += __popc(s3.y ^ w3[1]);
    c += __popc(s3.z ^ w3[2]);
    c += __popc(s3.w ^ w3[3]);
    return a + c;
}

__device__ __forceinline__ int bdot4u(uint4 s0, uint4 s1, uint4 s2, uint4 s3,
                                      uint4 w0, uint4 w1, uint4 w2, uint4 w3) {
    int a = __popc(s0.x ^ w0.x);
    a += __popc(s0.y ^ w0.y);
    a += __popc(s0.z ^ w0.z);
    a += __popc(s0.w ^ w0.w);
    a += __popc(s1.x ^ w1.x);
    a += __popc(s1.y ^ w1.y);
    a += __popc(s1.z ^ w1.z);
    a += __popc(s1.w ^ w1.w);
    int c = __popc(s2.x ^ w2.x);
    c += __popc(s2.y ^ w2.y);
    c += __popc(s2.z ^ w2.z);
    c += __popc(s2.w ^ w2.w);
    c += __popc(s3.x ^ w3.x);
    c += __popc(s3.y ^ w3.y);
    c += __popc(s3.z ^ w3.z);
    c += __popc(s3.w ^ w3.w);
    return a + c;
}

// LDS-visibility barrier WITHOUT draining vmcnt (global logit stores stay in flight)
#define SYNCB asm volatile("s_waitcnt lgkmcnt(0)\n\ts_barrier" ::: "memory")

// ---- main persistent RNN kernel: 1 workgroup (512 thr, 8 waves) per chain ----
// 137 KB dynamic LDS caps occupancy at 1 block/CU (2 waves/EU): the backend's
// occupancy heuristic can no longer profit from low VGPR counts (rounds 1-7:
// it spilled the weight block to scratch -> 1.28 GB FETCH of L2 re-reads,
// ~650 cyc/layer). Layers 0-3 weights live in LDS (no heuristic can evict
// LDS); layers 4-6 (48 VGPRs) stay register-pinned via volatile asm loads.
__attribute__((amdgpu_flat_work_group_size(512, 512), amdgpu_waves_per_eu(2, 2)))
__global__ void brnn_kernel(const int* __restrict__ tokens,
                            const uint32_t* __restrict__ ffq,
                            const int* __restrict__ ithr,
                            const uint32_t* __restrict__ embp,
                            const uint32_t* __restrict__ headp,
                            const uint32_t* __restrict__ initp,
                            float* __restrict__ out) {
    extern __shared__ uint32_t sm[];
    const int b = blockIdx.x;
    const int tid = threadIdx.x;      // == output column for this thread
    const int wv = tid >> 6;
    const int lane = tid & 63;

    uint4* const xq0p = (uint4*)&sm[XQ0W];
    uint4* const xq1p = (uint4*)&sm[XQ1W];
    uint4* const wbase = (uint4*)&sm[WOFF] + tid;  // chunk c at wbase[c*512]

    // layers 4-6 weights: 12 chunks = 48 VGPRs, asm-pinned (unsinkable).
    u32x4 W40, W41, W42, W43, W50, W51, W52, W53, W60, W61, W62, W63;
#define WLOAD(V, L, Q) asm volatile("global_load_dwordx4 %0, %1, off" \
        : "=v"(V) : "v"(ffq + ((L) * 4 + (Q)) * (DM * 4) + tid * 4))
    WLOAD(W40, 4, 0); WLOAD(W41, 4, 1); WLOAD(W42, 4, 2); WLOAD(W43, 4, 3);
    WLOAD(W50, 5, 0); WLOAD(W51, 5, 1); WLOAD(W52, 5, 2); WLOAD(W53, 5, 3);
    WLOAD(W60, 6, 0); WLOAD(W61, 6, 1); WLOAD(W62, 6, 2); WLOAD(W63, 6, 3);
#undef WLOAD

    // stage layers 0-3 weights into LDS ([chunk][tid] b128 layout, 2-way-free)
    {
        const uint4* src = (const uint4*)ffq + tid;
        uint4* dst = (uint4*)&sm[WOFF] + tid;
#pragma unroll
        for (int c = 0; c < 16; ++c)
            dst[c * 512] = src[c * 512];
    }

    const int it0 = ithr[0 * DM + tid];
    const int it1 = ithr[1 * DM + tid];
    const int it2 = ithr[2 * DM + tid];
    const int it3 = ithr[3 * DM + tid];
    const int it4 = ithr[4 * DM + tid];
    const int it5 = ithr[5 * DM + tid];
    const int it6 = ithr[6 * DM + tid];

    // head weights: vocab v = 16*wv + (lane&15), used by lanes 0..15 of each wave
    const int hvv = (wv << 4) | (lane & 15);
    const uint32_t h0 = headp[0 * VOCABN + hvv];
    const uint32_t h1 = headp[1 * VOCABN + hvv];
    const uint32_t h2 = headp[2 * VOCABN + hvv];
    const uint32_t h3 = headp[3 * VOCABN + hvv];

    sm[EMBW + tid] = embp[tid];
    sm[TOKW + tid] = (uint32_t)tokens[b * TLEN + tid];
    sm[TOKW + tid + 512] = (uint32_t)tokens[b * TLEN + tid + 512];
    if (tid == 0) { sm[TOKW + TLEN] = 0; sm[TOKW + TLEN + 1] = 0; }
    if (tid < 16) sm[XQ0W + tid] = initp[tid];
    asm volatile("s_waitcnt vmcnt(0)" ::: "memory");
    __syncthreads();
    if (tid < 4) sm[XQ0W + 12 + tid] = sm[EMBW + sm[TOKW] * 4 + tid];
    __syncthreads();

    float* outb = out + (size_t)b * TLEN * VOCABN;

#define LDSLAYER(L, SRCQ, DSTQ) do {                                           \
        uint4 s0 = (SRCQ)[0], s1 = (SRCQ)[1], s2 = (SRCQ)[2], s3 = (SRCQ)[3]; \
        uint4 w0 = wbase[((L) * 4 + 0) * 512];                                 \
        uint4 w1 = wbase[((L) * 4 + 1) * 512];                                 \
        uint4 w2 = wbase[((L) * 4 + 2) * 512];                                 \
        uint4 w3 = wbase[((L) * 4 + 3) * 512];                                 \
        int acc = bdot4u(s0, s1, s2, s3, w0, w1, w2, w3);                      \
        unsigned long long m = __ballot(acc <= it##L);                         \
        if (lane == 0)                                                         \
            ((uint2*)(DSTQ))[wv] = make_uint2((uint32_t)m, (uint32_t)(m >> 32)); \
        SYNCB;                                                                 \
    } while (0)

#define REGLAYER(L, SRCQ, DSTQ) do {                                           \
        uint4 s0 = (SRCQ)[0], s1 = (SRCQ)[1], s2 = (SRCQ)[2], s3 = (SRCQ)[3]; \
        int acc = bdot4r(s0, s1, s2, s3, W##L##0, W##L##1, W##L##2, W##L##3);  \
        unsigned long long m = __ballot(acc <= it##L);                         \
        if (lane == 0)                                                         \
            ((uint2*)(DSTQ))[wv] = make_uint2((uint32_t)m, (uint32_t)(m >> 32)); \
        SYNCB;                                                                 \
    } while (0)

#define LAYERF(SRCQ, DSTQ) do {                                                \
        uint4 s0 = (SRCQ)[0], s1 = (SRCQ)[1], s2 = (SRCQ)[2], s3 = (SRCQ)[3]; \
        int acc = bdot4r(s0, s1, s2, s3, W60, W61, W62, W63);                  \
        unsigned long long m = __ballot(acc <= it6);                           \
        if (lane == 0) {                                                       \
            uint2 v_ = make_uint2((uint32_t)m, (uint32_t)(m >> 32));           \
            if (wv < 6) ((uint2*)(DSTQ))[wv] = v_;                             \
            else ((uint2*)&sm[HXW])[wv - 6] = v_;                              \
        }                                                                      \
        if (wv == 7 && lane < 4) ((uint32_t*)(DSTQ))[12 + lane] = embw;        \
        SYNCB;                                                                 \
    } while (0)

#define STEP(AQ, BQ, T) do {                                                   \
        /* prefetch next token's embedding early (wave 7 only) */              \
        uint32_t embw = 0;                                                     \
        if (wv == 7) embw = sm[EMBW + sm[TOKW + (T) + 1] * 4 + (lane & 3)];    \
        LDSLAYER(0, AQ, BQ);                                                   \
        LDSLAYER(1, BQ, AQ);                                                   \
        LDSLAYER(2, AQ, BQ);                                                   \
        LDSLAYER(3, BQ, AQ);                                                   \
        REGLAYER(4, AQ, BQ);                                                   \
        REGLAYER(5, BQ, AQ);                                                   \
        LAYERF(AQ, BQ);                                                        \
        uint4 hv_ = *(const uint4*)&sm[HXW];                                   \
        if (lane < 16) {                                                       \
            int hc = __popc(hv_.x ^ h0) + __popc(hv_.y ^ h1) +                 \
                     __popc(hv_.z ^ h2) + __popc(hv_.w ^ h3);                  \
            outb[(T) * VOCABN + hvv] = (float)(RD - 2 * hc);                   \
        }                                                                      \
    } while (0)

    for (int t = 0; t < TLEN; t += 2) {
        STEP(xq0p, xq1p, t);
        STEP(xq1p, xq0p, t + 1);
    }
#undef LDSLAYER
#undef REGLAYER
#undef LAYERF
#undef STEP
}

extern "C" void kernel_launch(void* const* d_in, const int* in_sizes, int n_in,
                              void* d_out, int out_size, void* d_ws, size_t ws_size,
                              hipStream_t stream) {
    const int* tokens = (const int*)d_in[0];
    const float* initial = (const float*)d_in[1];
    const float* embed = (const float*)d_in[2];
    const float* ff = (const float*)d_in[3];
    const float* ff_thresh = (const float*)d_in[4];
    const float* head = (const float*)d_in[5];
    float* out = (float*)d_out;

    uint32_t* ffq = (uint32_t*)d_ws;              // 7*16*512 = 57344 words (16B-aligned chunks)
    uint32_t* embp = ffq + NUM_FF * 16 * DM;      // 512 words
    uint32_t* headp = embp + 512;                 // 512 words
    uint32_t* initp = headp + 512;                // 16 words
    int* ithr = (int*)(initp + 16);               // 7*512 ints

    // raise the dynamic-LDS cap (host-side, idempotent, capture-safe)
    (void)hipFuncSetAttribute((const void*)brnn_kernel,
                              hipFuncAttributeMaxDynamicSharedMemorySize, SMBYTES);

    pack_ff_kernel<<<(NUM_FF * 16 * DM + 255) / 256, 256, 0, stream>>>(ff, ffq);
    pack_thresh_kernel<<<(NUM_FF * DM + 255) / 256, 256, 0, stream>>>(ff_thresh, ithr);
    pack_small_kernel<<<1, 512, 0, stream>>>(embed, head, initial, embp, headp, initp);
    brnn_kernel<<<BATCH, 512, SMBYTES, stream>>>(tokens, ffq, ithr, embp, headp, initp, out);
}